// Round 13
// baseline (116.497 us; speedup 1.0000x reference)
//
#include <hip/hip_runtime.h>
#include <hip/hip_bf16.h>

// out[n] = sum_m coefs[m] * exp(-||L_m^T (x_n - c_m)||^2),  coefs[m]=softmax(w)[m]*|det L_m|
// N=131072, M=32, D=32, f32.
//
// Round 13: ILP attack. r12 (swapped MFMA + shfl epilogue) passed post-timing and
// won 5.8us; main still ~36us vs ~4us pipe model -> per-m chains too long for 4
// waves/SIMD. Changes:
//  - gmm_main: process TWO m per iteration with independent register sets
//    (8 MFMA chains x depth 3, 24 MFMA/iter/wave). No software pipeline, no
//    register rotation (r10 lesson). VGPR ~110 < 128 cap.
//  - gmm_pre: 256 threads, coalesced float4 stage of L into LDS, parallelized
//    fragment split (was 64-thr serial uncoalesced, suspected 10-20us).

#define D 32
#define M 32
#define WT 2  // point-tiles (of 16) per wave

typedef __attribute__((ext_vector_type(8))) short short8;
typedef __attribute__((ext_vector_type(4))) float f32x4;

__device__ __forceinline__ unsigned short f2bf_rne(float f) {
  unsigned int u = __float_as_uint(f);
  return (unsigned short)((u + 0x7FFFu + ((u >> 16) & 1u)) >> 16);
}

#define SCL 1.2011224087864498f  // sqrt(log2(e))

__global__ __launch_bounds__(256) void gmm_pre(
    const float* __restrict__ centers, const float* __restrict__ L,
    const float* __restrict__ weights,
    float* __restrict__ CNf, float* __restrict__ LC,
    unsigned short* __restrict__ LH, unsigned short* __restrict__ LL) {
  __shared__ float Ls[D * D];
  __shared__ float U[D][D + 1];
  __shared__ float C2s[D];
  const int m = blockIdx.x;
  const int t = threadIdx.x;
  const float* Lm = L + m * (D * D);

  // coalesced stage of L_m into LDS (1024 floats, 256 thr x float4)
  reinterpret_cast<float4*>(Ls)[t] = reinterpret_cast<const float4*>(Lm)[t];
  __syncthreads();

  if (t < D) {
    for (int k = 0; k < D; ++k) U[t][k] = Ls[t * D + k];
    float acc = 0.f;
    for (int d = 0; d < D; ++d) acc = fmaf(centers[m * D + d], Ls[d * D + t], acc);
    C2s[t] = acc;                       // (L^T c)_t, unscaled
    CNf[m * D + t] = -SCL * acc;        // bias in k-natural order
  }

  // fragment split of (SCL*L), layout [m][ktile][lane][j]; 1024 elems / 256 thr
#pragma unroll
  for (int i = 0; i < 4; ++i) {
    const int e = t * 4 + i;
    const int j = e & 7;
    const int lane = (e >> 3) & 63;
    const int kt = e >> 9;
    const int d = 8 * (lane >> 4) + j;
    const int k = kt * 16 + (lane & 15);
    float v = Ls[d * D + k] * SCL;
    unsigned int hi = __float_as_uint(v) & 0xFFFF0000u;
    float lo = v - __uint_as_float(hi);
    size_t off = (((size_t)(m * 2 + kt)) * 64 + lane) * 8 + j;
    LH[off] = (unsigned short)(hi >> 16);
    LL[off] = f2bf_rne(lo);
  }
  __syncthreads();

  // LU (no pivot; L ~ I + 0.05*noise) for |det|
  for (int p = 0; p < D - 1; ++p) {
    if (t > p && t < D) {
      float f = U[t][p] / U[p][p];
      for (int k = p; k < D; ++k) U[t][k] -= f * U[p][k];
    }
    __syncthreads();
  }
  if (t == 0) {
    float det = 1.f;
    for (int i = 0; i < D; ++i) det *= U[i][i];
    float mx = -1e30f;
    for (int j = 0; j < M; ++j) mx = fmaxf(mx, weights[j]);
    float s = 0.f;
    for (int j = 0; j < M; ++j) s += __expf(weights[j] - mx);
    float coef = (__expf(weights[m] - mx) / s) * fabsf(det);
    LC[m] = log2f(coef);
  }
}

__global__ __launch_bounds__(1024, 4) void gmm_main(
    const float* __restrict__ points,
    const float* __restrict__ CNf, const float* __restrict__ LC,
    const unsigned short* __restrict__ LH, const unsigned short* __restrict__ LL,
    float* __restrict__ out, int N) {
  // 132 KB LDS: whole fragment + bias tables resident per CU
  __shared__ unsigned short sLH[M * 2 * 64 * 8];  // 64 KB
  __shared__ unsigned short sLL[M * 2 * 64 * 8];  // 64 KB
  __shared__ float sCNf[M * D];                   // 4 KB

  const int tid = threadIdx.x;
  const int lane = tid & 63;
  const int wave = tid >> 6;  // 0..15
  const int col = lane & 15;  // x-frag: point; L-frag: k
  const int g = lane >> 4;    // d-slot base 8g; D rows k = 4g+reg (+16 per k-tile)

  // ---- one-time stage: 128 KB fragments + 4 KB bias into LDS ----
  {
    const uint4* src = reinterpret_cast<const uint4*>(LH);
    uint4* dst = reinterpret_cast<uint4*>(sLH);
#pragma unroll
    for (int i = 0; i < 4; ++i) dst[tid + i * 1024] = src[tid + i * 1024];
    src = reinterpret_cast<const uint4*>(LL);
    dst = reinterpret_cast<uint4*>(sLL);
#pragma unroll
    for (int i = 0; i < 4; ++i) dst[tid + i * 1024] = src[tid + i * 1024];
    if (tid < M * D / 4) {
      reinterpret_cast<float4*>(sCNf)[tid] =
          reinterpret_cast<const float4*>(CNf)[tid];
    }
  }

  const int tileBase = (blockIdx.x * 16 + wave) * (WT * 16);

  // ---- load X tiles, Dekker-split into bf16 hi/lo fragments (B-operand) ----
  short8 xh0, xl0, xh1, xl1;
#pragma unroll
  for (int t = 0; t < WT; ++t) {
    const float* p = points + (size_t)(tileBase + t * 16 + col) * D + 8 * g;
    float4 a = *reinterpret_cast<const float4*>(p);
    float4 b = *reinterpret_cast<const float4*>(p + 4);
    float v[8] = {a.x, a.y, a.z, a.w, b.x, b.y, b.z, b.w};
    unsigned int hiu[8];
    unsigned int lou[8];
#pragma unroll
    for (int j = 0; j < 8; ++j) {
      unsigned int u = __float_as_uint(v[j]);
      hiu[j] = u & 0xFFFF0000u;  // exact split
      lou[j] = __float_as_uint(v[j] - __uint_as_float(hiu[j]));
    }
    union { short8 s; unsigned int w[4]; } H, Lo;
#pragma unroll
    for (int jj = 0; jj < 4; ++jj) {
      H.w[jj]  = __builtin_amdgcn_perm(hiu[2 * jj + 1], hiu[2 * jj], 0x07060302);
      Lo.w[jj] = __builtin_amdgcn_perm(lou[2 * jj + 1], lou[2 * jj], 0x07060302);
    }
    if (t == 0) { xh0 = H.s; xl0 = Lo.s; } else { xh1 = H.s; xl1 = Lo.s; }
  }

  __syncthreads();  // LDS tables ready

  float result0 = 0.f, result1 = 0.f;

  const short8* bh_base = reinterpret_cast<const short8*>(sLH);
  const short8* bl_base = reinterpret_cast<const short8*>(sLL);
  const float4* cn_base = reinterpret_cast<const float4*>(sCNf);

  // ---- dual-m loop: two independent register sets per iteration ----
#pragma unroll 1
  for (int mp = 0; mp < M; mp += 2) {
    const int ma = mp, mb = mp + 1;
    // m_a fragments
    short8 Abh0 = bh_base[(ma * 2 + 0) * 64 + lane];
    short8 Abh1 = bh_base[(ma * 2 + 1) * 64 + lane];
    short8 Abl0 = bl_base[(ma * 2 + 0) * 64 + lane];
    short8 Abl1 = bl_base[(ma * 2 + 1) * 64 + lane];
    // m_b fragments
    short8 Bbh0 = bh_base[(mb * 2 + 0) * 64 + lane];
    short8 Bbh1 = bh_base[(mb * 2 + 1) * 64 + lane];
    short8 Bbl0 = bl_base[(mb * 2 + 0) * 64 + lane];
    short8 Bbl1 = bl_base[(mb * 2 + 1) * 64 + lane];
    float4 Acn0 = cn_base[ma * 8 + g];
    float4 Acn1 = cn_base[ma * 8 + 4 + g];
    float4 Bcn0 = cn_base[mb * 8 + g];
    float4 Bcn1 = cn_base[mb * 8 + 4 + g];
    const float lca = LC[ma];
    const float lcb = LC[mb];

    f32x4 Aa00 = (f32x4){Acn0.x, Acn0.y, Acn0.z, Acn0.w};
    f32x4 Aa01 = (f32x4){Acn1.x, Acn1.y, Acn1.z, Acn1.w};
    f32x4 Aa10 = Aa00;
    f32x4 Aa11 = Aa01;
    f32x4 Ba00 = (f32x4){Bcn0.x, Bcn0.y, Bcn0.z, Bcn0.w};
    f32x4 Ba01 = (f32x4){Bcn1.x, Bcn1.y, Bcn1.z, Bcn1.w};
    f32x4 Ba10 = Ba00;
    f32x4 Ba11 = Ba01;

    // 24 MFMAs, 8 independent chains of depth 3 (interleaved a/b)
    Aa00 = __builtin_amdgcn_mfma_f32_16x16x32_bf16(Abh0, xh0, Aa00, 0, 0, 0);
    Ba00 = __builtin_amdgcn_mfma_f32_16x16x32_bf16(Bbh0, xh0, Ba00, 0, 0, 0);
    Aa01 = __builtin_amdgcn_mfma_f32_16x16x32_bf16(Abh1, xh0, Aa01, 0, 0, 0);
    Ba01 = __builtin_amdgcn_mfma_f32_16x16x32_bf16(Bbh1, xh0, Ba01, 0, 0, 0);
    Aa10 = __builtin_amdgcn_mfma_f32_16x16x32_bf16(Abh0, xh1, Aa10, 0, 0, 0);
    Ba10 = __builtin_amdgcn_mfma_f32_16x16x32_bf16(Bbh0, xh1, Ba10, 0, 0, 0);
    Aa11 = __builtin_amdgcn_mfma_f32_16x16x32_bf16(Abh1, xh1, Aa11, 0, 0, 0);
    Ba11 = __builtin_amdgcn_mfma_f32_16x16x32_bf16(Bbh1, xh1, Ba11, 0, 0, 0);

    Aa00 = __builtin_amdgcn_mfma_f32_16x16x32_bf16(Abl0, xh0, Aa00, 0, 0, 0);
    Ba00 = __builtin_amdgcn_mfma_f32_16x16x32_bf16(Bbl0, xh0, Ba00, 0, 0, 0);
    Aa01 = __builtin_amdgcn_mfma_f32_16x16x32_bf16(Abl1, xh0, Aa01, 0, 0, 0);
    Ba01 = __builtin_amdgcn_mfma_f32_16x16x32_bf16(Bbl1, xh0, Ba01, 0, 0, 0);
    Aa10 = __builtin_amdgcn_mfma_f32_16x16x32_bf16(Abl0, xh1, Aa10, 0, 0, 0);
    Ba10 = __builtin_amdgcn_mfma_f32_16x16x32_bf16(Bbl0, xh1, Ba10, 0, 0, 0);
    Aa11 = __builtin_amdgcn_mfma_f32_16x16x32_bf16(Abl1, xh1, Aa11, 0, 0, 0);
    Ba11 = __builtin_amdgcn_mfma_f32_16x16x32_bf16(Bbl1, xh1, Ba11, 0, 0, 0);

    Aa00 = __builtin_amdgcn_mfma_f32_16x16x32_bf16(Abh0, xl0, Aa00, 0, 0, 0);
    Ba00 = __builtin_amdgcn_mfma_f32_16x16x32_bf16(Bbh0, xl0, Ba00, 0, 0, 0);
    Aa01 = __builtin_amdgcn_mfma_f32_16x16x32_bf16(Abh1, xl0, Aa01, 0, 0, 0);
    Ba01 = __builtin_amdgcn_mfma_f32_16x16x32_bf16(Bbh1, xl0, Ba01, 0, 0, 0);
    Aa10 = __builtin_amdgcn_mfma_f32_16x16x32_bf16(Abh0, xl1, Aa10, 0, 0, 0);
    Ba10 = __builtin_amdgcn_mfma_f32_16x16x32_bf16(Bbh0, xl1, Ba10, 0, 0, 0);
    Aa11 = __builtin_amdgcn_mfma_f32_16x16x32_bf16(Abh1, xl1, Aa11, 0, 0, 0);
    Ba11 = __builtin_amdgcn_mfma_f32_16x16x32_bf16(Bbh1, xl1, Ba11, 0, 0, 0);

    // epilogues (4 independent)
    {
      float u = fmaf(Aa00[0], Aa00[0], Aa00[1] * Aa00[1]);
      u = fmaf(Aa00[2], Aa00[2], u);
      u = fmaf(Aa00[3], Aa00[3], u);
      float v = fmaf(Aa01[0], Aa01[0], Aa01[1] * Aa01[1]);
      v = fmaf(Aa01[2], Aa01[2], v);
      v = fmaf(Aa01[3], Aa01[3], v);
      float s = u + v;
      s += __shfl_xor(s, 16);
      s += __shfl_xor(s, 32);
      result0 += exp2f(lca - s);
    }
    {
      float u = fmaf(Aa10[0], Aa10[0], Aa10[1] * Aa10[1]);
      u = fmaf(Aa10[2], Aa10[2], u);
      u = fmaf(Aa10[3], Aa10[3], u);
      float v = fmaf(Aa11[0], Aa11[0], Aa11[1] * Aa11[1]);
      v = fmaf(Aa11[2], Aa11[2], v);
      v = fmaf(Aa11[3], Aa11[3], v);
      float s = u + v;
      s += __shfl_xor(s, 16);
      s += __shfl_xor(s, 32);
      result1 += exp2f(lca - s);
    }
    {
      float u = fmaf(Ba00[0], Ba00[0], Ba00[1] * Ba00[1]);
      u = fmaf(Ba00[2], Ba00[2], u);
      u = fmaf(Ba00[3], Ba00[3], u);
      float v = fmaf(Ba01[0], Ba01[0], Ba01[1] * Ba01[1]);
      v = fmaf(Ba01[2], Ba01[2], v);
      v = fmaf(Ba01[3], Ba01[3], v);
      float s = u + v;
      s += __shfl_xor(s, 16);
      s += __shfl_xor(s, 32);
      result0 += exp2f(lcb - s);
    }
    {
      float u = fmaf(Ba10[0], Ba10[0], Ba10[1] * Ba10[1]);
      u = fmaf(Ba10[2], Ba10[2], u);
      u = fmaf(Ba10[3], Ba10[3], u);
      float v = fmaf(Ba11[0], Ba11[0], Ba11[1] * Ba11[1]);
      v = fmaf(Ba11[2], Ba11[2], v);
      v = fmaf(Ba11[3], Ba11[3], v);
      float s = u + v;
      s += __shfl_xor(s, 16);
      s += __shfl_xor(s, 32);
      result1 += exp2f(lcb - s);
    }
  }

  // all lanes hold full sums; lanes 0..15 write 16 contiguous floats per tile
  if (lane < 16) {
    out[tileBase + col] = result0;
    out[tileBase + 16 + col] = result1;
  }
}

extern "C" void kernel_launch(void* const* d_in, const int* in_sizes, int n_in,
                              void* d_out, int out_size, void* d_ws, size_t ws_size,
                              hipStream_t stream) {
  const float* points  = (const float*)d_in[0];
  const float* centers = (const float*)d_in[1];
  const float* L       = (const float*)d_in[2];
  const float* weights = (const float*)d_in[3];
  float* out = (float*)d_out;
  const int N = in_sizes[0] / D;

  char* ws = (char*)d_ws;
  float* CNf          = (float*)ws;                     // 32*32*4 = 4096 B
  float* LC           = (float*)(ws + 4096);            // 128 B
  unsigned short* LHf = (unsigned short*)(ws + 8192);   // 65536 B
  unsigned short* LLf = (unsigned short*)(ws + 8192 + 65536);

  gmm_pre<<<M, 256, 0, stream>>>(centers, L, weights, CNf, LC, LHf, LLf);

  // 1024 threads = 16 waves; 512 points per block; grid = 256 = 1 block/CU
  gmm_main<<<N / (16 * WT * 16), 1024, 0, stream>>>(
      points, CNf, LC, LHf, LLf, out, N);
}